// Round 20
// baseline (78.739 us; speedup 1.0000x reference)
//
#include <hip/hip_runtime.h>

// Pfaffian of 128 gathered 128x128 skew-symmetric f32 matrices, Parlett-Reid
// LTL^T. One 1024-thread block per matrix (16 waves = 4 waves/SIMD for
// latency hiding — the one untried axis; r13-r19 ran 2 waves/SIMD and
// plateaued at 75.6-78.1us with ~1500 cyc/window of unhidden latency).
// 4-step look-ahead panel pipeline: crew (wave 0) computes panel P+1's
// tau/col while bulk (waves 1-15) applies panel P; ONE barrier per window.
//
// NUMERICS LEDGER (rounds 0-19): np ref is the XLA-CPU f32 trajectory:
//     tmp = fma(tau_r, col_c, A);  A' = fma(-col_r, tau_c, tmp)
// tau = __fdiv_rn(row_k, piv), pf = __fmul_rn in step order. Rounds 5-19
// PASSED with absmax 0.0234375 (bit-stable fingerprint). Dead indices
// staged/published as exact 0.0f -> identity FMAs on never-read entries;
// stale dead-row rS/cS entries are zero-masked on publish (certified).
// Ownership remap changes WHO computes, not values/order -> bit-identical.
//
// Layout: rg = t>>4 (0..63) owns rows [2rg, 2rg+2); cg = t&15 owns cols
// [8cg, 8cg+8); A[2][8]. Wave w owns rows [8w, 8w+8) -> bulk alive iff
// wave > P. stage(Pn) publishers: rows rg in [4Pn, 4Pn+4) (wave Pn, alive
// at window Pn-2), cols cg==Pn (all alive waves contribute their rows;
// dead-row entries are only ever consumed through the zero-mask).
//
// PERF LEDGER: r8 50.6 -> r9 47 -> r11 41 -> r12 ~29 -> r13 76.1 bench ->
// r17 broadcast pre-update 75.6 (BEST) -> r18 8-step panels 78.1 (crew
// scales) -> r19 setprio neutral 76.0 (crew latency- not arbitration-
// bound). r20 = r17 + 1024 threads (2x8 blocks).

#define POFF(i) ((i) + (((i) >> 5) << 2))   // 4-float pad every 32 floats
#define RL(v, l) __int_as_float(__builtin_amdgcn_readlane(__float_as_int(v), (l)))

__global__ __launch_bounds__(1024) void pfaffian_kernel(
    const float* __restrict__ x,    // [128, 128]
    const float* __restrict__ F,    // [32640] packed strict lower tri of 256x256
    float* __restrict__ out)        // [128]
{
    const int b    = blockIdx.x;
    const int t    = threadIdx.x;
    const int lane = t & 63;
    const int wave = t >> 6;        // 0..15

    __shared__ int idx_sh[128];
    __shared__ int wtot[4];
    __shared__ __align__(16) float tauLDS[2][4][144];
    __shared__ __align__(16) float colLDS[2][4][144];
    __shared__ __align__(16) float rS[2][4][144];   // panel row vecs k0,k0+2,k0+4,k0+6
    __shared__ __align__(16) float cS[2][4][144];   // panel col vecs k0+1,+3,+5,+7

    // ---- occupancy -> sorted index list (certified r0-r19) ----
    if (t < 256) {
        const float xv  = x[b * 128 + (t & 127)];
        const bool  pos = xv > 0.0f;
        const bool  o   = (t < 128) ? pos : !pos;
        const unsigned long long mm = __ballot(o);
        const int rank = __popcll(mm & ((1ull << lane) - 1ull));
        if (lane == 63) wtot[wave] = rank + (o ? 1 : 0);
        __syncthreads();
        int off = 0;
#pragma unroll
        for (int w = 0; w < 4; ++w)
            if (w < wave) off += wtot[w];
        if (o) idx_sh[off + rank] = t;
    } else {
        __syncthreads();   // matches the barrier inside the t<256 branch
    }
    __syncthreads();

    // ---- 2x8 block ownership ----
    const int rg   = t >> 4;        // rows [2rg, 2rg+2)
    const int cg   = t & 15;        // cols [8cg, 8cg+8)
    const int row0 = rg << 1;
    const int col0 = cg << 3;
    const int prow = POFF(row0);    // even pair: never straddles a pad block
    const int pcol = POFF(col0);

    int ri[2], ci[8];
#pragma unroll
    for (int a = 0; a < 2; ++a) ri[a] = idx_sh[row0 + a];
#pragma unroll
    for (int c = 0; c < 8; ++c) ci[c] = idx_sh[col0 + c];

    float A[2][8];
#pragma unroll
    for (int a = 0; a < 2; ++a) {
        const int ii = ri[a];
#pragma unroll
        for (int c = 0; c < 8; ++c) {
            const int jj = ci[c];
            const int hi = ii > jj ? ii : jj;
            const int lo = ii > jj ? jj : ii;
            float v = (ii == jj) ? 0.0f : F[(hi * (hi - 1)) / 2 + lo];
            A[a][c] = (ii < jj) ? -v : v;
        }
    }

    // stage panel Pn into set st: row vecs 8Pn+2d (d=0..3) from rg=4Pn+d
    // (local row 0); col vecs 8Pn+2m+1 (m=0..3) from cg==Pn (local cols
    // 1,3,5,7; each thread contributes its 2 rows as a float2).
    auto stage = [&](int Pn, int st) {
        const int d = rg - 4 * Pn;
        if (d >= 0 && d < 4) {
            *(float4*)&rS[st][d][pcol]     = make_float4(A[0][0], A[0][1], A[0][2], A[0][3]);
            *(float4*)&rS[st][d][pcol + 4] = make_float4(A[0][4], A[0][5], A[0][6], A[0][7]);
        }
        if (cg == Pn) {
            *(float2*)&cS[st][0][prow] = make_float2(A[0][1], A[1][1]);
            *(float2*)&cS[st][1][prow] = make_float2(A[0][3], A[1][3]);
            *(float2*)&cS[st][2][prow] = make_float2(A[0][5], A[1][5]);
            *(float2*)&cS[st][3][prow] = make_float2(A[0][7], A[1][7]);
        }
    };
    stage(0, 0);   // panel 0 raw (all threads execute: prologue)
    stage(1, 1);   // panel 1 raw
    __syncthreads();

    float pf = 1.0f;

    // crew for panel Pn (lane-indexed only — independent of block layout):
    // pre-update with panel Pn-1 from tauLDS/colLDS[sv^1] via broadcast
    // loads, chain 4 steps, publish into set sv.
    auto crew = [&](int Pn, bool pre) {
        const int sv = Pn & 1;
        const int g0 = lane << 1;
        const int g1 = g0 + 1;
        const int pg = POFF(g0);
        float R[4][2], C[4][2];
#pragma unroll
        for (int j = 0; j < 4; ++j) {
            const float2 rv = *(const float2*)&rS[sv][j][pg];
            const float2 cv = *(const float2*)&cS[sv][j][pg];
            R[j][0] = rv.x; R[j][1] = rv.y;
            C[j][0] = cv.x; C[j][1] = cv.y;
        }
        if (pre) {
            const int svp  = sv ^ 1;
            const int base = POFF(8 * Pn);   // 8Pn..8Pn+7: inside one pad block
            float4 Tq[4][2], Cq[4][2];
#pragma unroll
            for (int jp = 0; jp < 4; ++jp) {   // batched broadcast loads
                Tq[jp][0] = *(const float4*)&tauLDS[svp][jp][base];
                Tq[jp][1] = *(const float4*)&tauLDS[svp][jp][base + 4];
                Cq[jp][0] = *(const float4*)&colLDS[svp][jp][base];
                Cq[jp][1] = *(const float4*)&colLDS[svp][jp][base + 4];
            }
#pragma unroll
            for (int jp = 0; jp < 4; ++jp) {
                const float trA[4] = {Tq[jp][0].x, Tq[jp][0].z, Tq[jp][1].x, Tq[jp][1].z};
                const float crA[4] = {Cq[jp][0].x, Cq[jp][0].z, Cq[jp][1].x, Cq[jp][1].z};
                const float tcA[4] = {Tq[jp][0].y, Tq[jp][0].w, Tq[jp][1].y, Tq[jp][1].w};
                const float ccA[4] = {Cq[jp][0].y, Cq[jp][0].w, Cq[jp][1].y, Cq[jp][1].w};
                const float2 tpv = *(const float2*)&tauLDS[svp][jp][pg];
                const float2 cpv = *(const float2*)&colLDS[svp][jp][pg];
#pragma unroll
                for (int a = 0; a < 4; ++a) {
                    const float tau_r = trA[a];
                    const float col_r = crA[a];
                    R[a][0] = __fmaf_rn(-col_r, tpv.x,
                              __fmaf_rn(tau_r, cpv.x, R[a][0]));
                    R[a][1] = __fmaf_rn(-col_r, tpv.y,
                              __fmaf_rn(tau_r, cpv.y, R[a][1]));
                    const float tau_c = tcA[a];
                    const float col_c = ccA[a];
                    C[a][0] = __fmaf_rn(-cpv.x, tau_c,
                              __fmaf_rn(tpv.x, col_c, C[a][0]));
                    C[a][1] = __fmaf_rn(-cpv.y, tau_c,
                              __fmaf_rn(tpv.y, col_c, C[a][1]));
                }
            }
        }
        float TAU[4][2], CV[4][2];
#pragma unroll
        for (int j = 0; j < 4; ++j) {
            const int k = 8 * Pn + 2 * j;
            const float piv = RL(R[j][1], 4 * Pn + j);
            pf = __fmul_rn(pf, piv);          // step order
            TAU[j][0] = (g0 > k + 1) ? __fdiv_rn(R[j][0], piv) : 0.0f;
            TAU[j][1] = (g1 > k + 1) ? __fdiv_rn(R[j][1], piv) : 0.0f;
            CV[j][0]  = (g0 > k + 1) ? C[j][0] : 0.0f;
            CV[j][1]  = (g1 > k + 1) ? C[j][1] : 0.0f;
            *(float2*)&tauLDS[sv][j][pg] = make_float2(TAU[j][0], TAU[j][1]);
            *(float2*)&colLDS[sv][j][pg] = make_float2(CV[j][0], CV[j][1]);
            // look-ahead: update later panel vectors with step j
#pragma unroll
            for (int j2 = j + 1; j2 < 4; ++j2) {
                const int ls = 4 * Pn + j2;
                const float tau_r = RL(TAU[j][0], ls);
                const float col_r = RL(CV[j][0], ls);
                R[j2][0] = __fmaf_rn(-col_r, TAU[j][0],
                           __fmaf_rn(tau_r, CV[j][0], R[j2][0]));
                R[j2][1] = __fmaf_rn(-col_r, TAU[j][1],
                           __fmaf_rn(tau_r, CV[j][1], R[j2][1]));
                const float tau_c = RL(TAU[j][1], ls);
                const float col_c = RL(CV[j][1], ls);
                C[j2][0] = __fmaf_rn(-CV[j][0], tau_c,
                           __fmaf_rn(TAU[j][0], col_c, C[j2][0]));
                C[j2][1] = __fmaf_rn(-CV[j][1], tau_c,
                           __fmaf_rn(TAU[j][1], col_c, C[j2][1]));
            }
        }
    };

    // ---- prologue: crew computes panel 0 from raw staged vectors ----
    if (wave == 0) crew(0, false);
    __syncthreads();

    // ---- 15 windows, ONE barrier each: bulk panel P || crew panel P+1 ----
    for (int P = 0; P < 15; ++P) {
        if (wave > P) {            // all of this wave's rows outlive panel P
            const int sp = P & 1;
#pragma unroll
            for (int j = 0; j < 4; ++j) {
                const float2 trv = *(const float2*)&tauLDS[sp][j][prow];
                const float2 crv = *(const float2*)&colLDS[sp][j][prow];
                const float4 t0v = *(const float4*)&tauLDS[sp][j][pcol];
                const float4 t1v = *(const float4*)&tauLDS[sp][j][pcol + 4];
                const float4 c0v = *(const float4*)&colLDS[sp][j][pcol];
                const float4 c1v = *(const float4*)&colLDS[sp][j][pcol + 4];
                const float tr[2] = {trv.x, trv.y};
                const float cr[2] = {crv.x, crv.y};
                const float tc[8] = {t0v.x, t0v.y, t0v.z, t0v.w,
                                     t1v.x, t1v.y, t1v.z, t1v.w};
                const float cc[8] = {c0v.x, c0v.y, c0v.z, c0v.w,
                                     c1v.x, c1v.y, c1v.z, c1v.w};
#pragma unroll
                for (int a = 0; a < 2; ++a) {
#pragma unroll
                    for (int c = 0; c < 8; ++c) {
                        A[a][c] = __fmaf_rn(-cr[a], tc[c],
                                  __fmaf_rn(tr[a], cc[c], A[a][c]));
                    }
                }
            }
            if (P <= 13) stage(P + 2, P & 1);   // updated through P
        }
        if (wave == 0) crew(P + 1, true);       // panels 1..15
        __syncthreads();
    }

    if (t == 0) out[b] = pf;
}

extern "C" void kernel_launch(void* const* d_in, const int* in_sizes, int n_in,
                              void* d_out, int out_size, void* d_ws, size_t ws_size,
                              hipStream_t stream) {
    const float* x = (const float*)d_in[0];   // [128*128]
    const float* F = (const float*)d_in[1];   // [32640]
    float* out     = (float*)d_out;           // [128]
    (void)in_sizes; (void)n_in; (void)out_size; (void)d_ws; (void)ws_size;

    pfaffian_kernel<<<128, 1024, 0, stream>>>(x, F, out);
}

// Round 21
// 75.936 us; speedup vs baseline: 1.0369x; 1.0369x over previous
//
#include <hip/hip_runtime.h>

// Pfaffian of 128 gathered 128x128 skew-symmetric f32 matrices, Parlett-Reid
// LTL^T. One 512-thread block per matrix. FINAL: r17 structure verbatim —
// the best-measured configuration (75.64us bench) after the full structural
// sweep (r13-r20: barriers/step 3->0.25, panel width 4/8, waves/SIMD 1/2/4,
// bulk+crew micro-opts). 4-step look-ahead panel pipeline: crew (wave 0)
// computes panel P+1's tau/col while bulk (waves 1-7) applies panel P; ONE
// barrier per window, 15 windows; crew pre-update via LDS broadcast loads.
//
// NUMERICS LEDGER (rounds 0-20): np ref is the XLA-CPU f32 trajectory:
//     tmp = fma(tau_r, col_c, A);  A' = fma(-col_r, tau_c, tmp)
// tau = __fdiv_rn(row_k, piv), pf = __fmul_rn in step order. Rounds 5-20
// PASSED with absmax 0.0234375 (bit-stable fingerprint). Dead indices
// staged/published as exact 0.0f -> identity FMAs on never-read entries.
// BIT-EXACTNESS IS LOAD-BEARING: the exact f64 value fails at 0.0908 >
// threshold 0.0684 — the algorithm's op schedule is frozen; only
// scheduling/layout may change.
//
// STRUCTURAL CEILING (r13-r20 evidence): kernel ~25us = 16 windows x ~3700
// cyc; window = max(crew serial chain ~1500, bulk ~1100) + barrier
// rendezvous + unhideable LDS round-trips. The 64-step serial dependency
// (pivot i+1 <- update i) with cross-thread broadcast each step is
// irreducible under the bit-exactness constraint. Bench metric adds ~50us
// of harness 268MB ws re-poison at 85% of achievable HBM BW (its own
// roofline, outside kernel control).
//
// PERF LEDGER: r8 50.6 -> r9 47 -> r11 41 -> r12 ~29 -> r13 76.1 bench ->
// r14 79.7 -> r15 77.3 -> r16 76.2 -> r17 75.6 (BEST) -> r18 78.1 ->
// r19 setprio 76.0 -> r20 1024thr 78.7 -> r21 = r17 restored.

#define POFF(i) ((i) + (((i) >> 5) << 2))   // 4-float pad every 32 floats
#define RL(v, l) __int_as_float(__builtin_amdgcn_readlane(__float_as_int(v), (l)))

__global__ __launch_bounds__(512) void pfaffian_kernel(
    const float* __restrict__ x,    // [128, 128]
    const float* __restrict__ F,    // [32640] packed strict lower tri of 256x256
    float* __restrict__ out)        // [128]
{
    const int b    = blockIdx.x;
    const int t    = threadIdx.x;
    const int lane = t & 63;
    const int wave = t >> 6;        // 0..7

    __shared__ int idx_sh[128];
    __shared__ int wtot[4];
    __shared__ __align__(16) float tauLDS[2][4][144];
    __shared__ __align__(16) float colLDS[2][4][144];
    __shared__ __align__(16) float rS[2][4][144];   // panel row vecs k0,k0+2,k0+4,k0+6
    __shared__ __align__(16) float cS[2][4][144];   // panel col vecs k0+1,+3,+5,+7

    // ---- occupancy -> sorted index list (certified r0-r20) ----
    if (t < 256) {
        const float xv  = x[b * 128 + (t & 127)];
        const bool  pos = xv > 0.0f;
        const bool  o   = (t < 128) ? pos : !pos;
        const unsigned long long mm = __ballot(o);
        const int rank = __popcll(mm & ((1ull << lane) - 1ull));
        if (lane == 63) wtot[wave] = rank + (o ? 1 : 0);
        __syncthreads();
        int off = 0;
#pragma unroll
        for (int w = 0; w < 4; ++w)
            if (w < wave) off += wtot[w];
        if (o) idx_sh[off + rank] = t;
    } else {
        __syncthreads();   // matches the barrier inside the t<256 branch
    }
    __syncthreads();

    // ---- 4x8 block ownership ----
    const int rg   = t >> 4;        // rows [rg*4, rg*4+4)
    const int cg   = t & 15;        // cols [cg*8, cg*8+8)
    const int row0 = rg << 2;
    const int col0 = cg << 3;
    const int prow = POFF(row0);
    const int pcol = POFF(col0);

    int ri[4], ci[8];
#pragma unroll
    for (int a = 0; a < 4; ++a) ri[a] = idx_sh[row0 + a];
#pragma unroll
    for (int c = 0; c < 8; ++c) ci[c] = idx_sh[col0 + c];

    float A[4][8];
#pragma unroll
    for (int a = 0; a < 4; ++a) {
        const int ii = ri[a];
#pragma unroll
        for (int c = 0; c < 8; ++c) {
            const int jj = ci[c];
            const int hi = ii > jj ? ii : jj;
            const int lo = ii > jj ? jj : ii;
            float v = (ii == jj) ? 0.0f : F[(hi * (hi - 1)) / 2 + lo];
            A[a][c] = (ii < jj) ? -v : v;
        }
    }

    // stage panel Pn (rgbase = 2*Pn, cgbase = Pn) into set st
    auto stage = [&](int Pn, int st) {
        const int rgbase = 2 * Pn;
        if (rg == rgbase) {
            *(float4*)&rS[st][0][pcol]     = make_float4(A[0][0], A[0][1], A[0][2], A[0][3]);
            *(float4*)&rS[st][0][pcol + 4] = make_float4(A[0][4], A[0][5], A[0][6], A[0][7]);
            *(float4*)&rS[st][1][pcol]     = make_float4(A[2][0], A[2][1], A[2][2], A[2][3]);
            *(float4*)&rS[st][1][pcol + 4] = make_float4(A[2][4], A[2][5], A[2][6], A[2][7]);
        }
        if (rg == rgbase + 1) {
            *(float4*)&rS[st][2][pcol]     = make_float4(A[0][0], A[0][1], A[0][2], A[0][3]);
            *(float4*)&rS[st][2][pcol + 4] = make_float4(A[0][4], A[0][5], A[0][6], A[0][7]);
            *(float4*)&rS[st][3][pcol]     = make_float4(A[2][0], A[2][1], A[2][2], A[2][3]);
            *(float4*)&rS[st][3][pcol + 4] = make_float4(A[2][4], A[2][5], A[2][6], A[2][7]);
        }
        if (cg == Pn) {
            *(float4*)&cS[st][0][prow] = make_float4(A[0][1], A[1][1], A[2][1], A[3][1]);
            *(float4*)&cS[st][1][prow] = make_float4(A[0][3], A[1][3], A[2][3], A[3][3]);
            *(float4*)&cS[st][2][prow] = make_float4(A[0][5], A[1][5], A[2][5], A[3][5]);
            *(float4*)&cS[st][3][prow] = make_float4(A[0][7], A[1][7], A[2][7], A[3][7]);
        }
    };
    stage(0, 0);   // panel 0 raw
    stage(1, 1);   // panel 1 raw
    __syncthreads();

    float pf = 1.0f;

    // crew for panel Pn: pre-update with panel Pn-1 (if pre) read from
    // tauLDS/colLDS[sv^1] via batched broadcast loads, chain 4 steps,
    // publish into set sv.
    auto crew = [&](int Pn, bool pre) {
        const int sv = Pn & 1;
        const int g0 = lane << 1;
        const int g1 = g0 + 1;
        const int pg = POFF(g0);
        float R[4][2], C[4][2];
#pragma unroll
        for (int j = 0; j < 4; ++j) {
            const float2 rv = *(const float2*)&rS[sv][j][pg];
            const float2 cv = *(const float2*)&cS[sv][j][pg];
            R[j][0] = rv.x; R[j][1] = rv.y;
            C[j][0] = cv.x; C[j][1] = cv.y;
        }
        if (pre) {
            const int svp  = sv ^ 1;
            const int base = POFF(8 * Pn);   // 8Pn..8Pn+7: inside one pad block
            float4 Tq[4][2], Cq[4][2];
#pragma unroll
            for (int jp = 0; jp < 4; ++jp) {   // batched broadcast loads
                Tq[jp][0] = *(const float4*)&tauLDS[svp][jp][base];
                Tq[jp][1] = *(const float4*)&tauLDS[svp][jp][base + 4];
                Cq[jp][0] = *(const float4*)&colLDS[svp][jp][base];
                Cq[jp][1] = *(const float4*)&colLDS[svp][jp][base + 4];
            }
#pragma unroll
            for (int jp = 0; jp < 4; ++jp) {
                const float trA[4] = {Tq[jp][0].x, Tq[jp][0].z, Tq[jp][1].x, Tq[jp][1].z};
                const float crA[4] = {Cq[jp][0].x, Cq[jp][0].z, Cq[jp][1].x, Cq[jp][1].z};
                const float tcA[4] = {Tq[jp][0].y, Tq[jp][0].w, Tq[jp][1].y, Tq[jp][1].w};
                const float ccA[4] = {Cq[jp][0].y, Cq[jp][0].w, Cq[jp][1].y, Cq[jp][1].w};
                const float2 tpv = *(const float2*)&tauLDS[svp][jp][pg];
                const float2 cpv = *(const float2*)&colLDS[svp][jp][pg];
#pragma unroll
                for (int a = 0; a < 4; ++a) {
                    const float tau_r = trA[a];   // == readlane(TAUp, row-lane)
                    const float col_r = crA[a];
                    R[a][0] = __fmaf_rn(-col_r, tpv.x,
                              __fmaf_rn(tau_r, cpv.x, R[a][0]));
                    R[a][1] = __fmaf_rn(-col_r, tpv.y,
                              __fmaf_rn(tau_r, cpv.y, R[a][1]));
                    const float tau_c = tcA[a];
                    const float col_c = ccA[a];
                    C[a][0] = __fmaf_rn(-cpv.x, tau_c,
                              __fmaf_rn(tpv.x, col_c, C[a][0]));
                    C[a][1] = __fmaf_rn(-cpv.y, tau_c,
                              __fmaf_rn(tpv.y, col_c, C[a][1]));
                }
            }
        }
        float TAU[4][2], CV[4][2];
#pragma unroll
        for (int j = 0; j < 4; ++j) {
            const int k = 8 * Pn + 2 * j;
            const float piv = RL(R[j][1], 4 * Pn + j);
            pf = __fmul_rn(pf, piv);          // step order
            TAU[j][0] = (g0 > k + 1) ? __fdiv_rn(R[j][0], piv) : 0.0f;
            TAU[j][1] = (g1 > k + 1) ? __fdiv_rn(R[j][1], piv) : 0.0f;
            CV[j][0]  = (g0 > k + 1) ? C[j][0] : 0.0f;
            CV[j][1]  = (g1 > k + 1) ? C[j][1] : 0.0f;
            *(float2*)&tauLDS[sv][j][pg] = make_float2(TAU[j][0], TAU[j][1]);
            *(float2*)&colLDS[sv][j][pg] = make_float2(CV[j][0], CV[j][1]);
            // look-ahead: update later panel vectors with step j
#pragma unroll
            for (int j2 = j + 1; j2 < 4; ++j2) {
                const int ls = 4 * Pn + j2;
                const float tau_r = RL(TAU[j][0], ls);
                const float col_r = RL(CV[j][0], ls);
                R[j2][0] = __fmaf_rn(-col_r, TAU[j][0],
                           __fmaf_rn(tau_r, CV[j][0], R[j2][0]));
                R[j2][1] = __fmaf_rn(-col_r, TAU[j][1],
                           __fmaf_rn(tau_r, CV[j][1], R[j2][1]));
                const float tau_c = RL(TAU[j][1], ls);
                const float col_c = RL(CV[j][1], ls);
                C[j2][0] = __fmaf_rn(-CV[j][0], tau_c,
                           __fmaf_rn(TAU[j][0], col_c, C[j2][0]));
                C[j2][1] = __fmaf_rn(-CV[j][1], tau_c,
                           __fmaf_rn(TAU[j][1], col_c, C[j2][1]));
            }
        }
    };

    // ---- prologue: crew computes panel 0 from raw staged vectors ----
    if (wave == 0) crew(0, false);
    __syncthreads();

    // ---- 15 windows, ONE barrier each: bulk panel P || crew panel P+1 ----
    for (int P = 0; P < 15; ++P) {
        if (wave >= 1 && 2 * wave > P) {
            const int sp = P & 1;
#pragma unroll
            for (int j = 0; j < 4; ++j) {
                const float4 trv = *(const float4*)&tauLDS[sp][j][prow];
                const float4 crv = *(const float4*)&colLDS[sp][j][prow];
                const float4 t0v = *(const float4*)&tauLDS[sp][j][pcol];
                const float4 t1v = *(const float4*)&tauLDS[sp][j][pcol + 4];
                const float4 c0v = *(const float4*)&colLDS[sp][j][pcol];
                const float4 c1v = *(const float4*)&colLDS[sp][j][pcol + 4];
                const float tr[4] = {trv.x, trv.y, trv.z, trv.w};
                const float cr[4] = {crv.x, crv.y, crv.z, crv.w};
                const float tc[8] = {t0v.x, t0v.y, t0v.z, t0v.w,
                                     t1v.x, t1v.y, t1v.z, t1v.w};
                const float cc[8] = {c0v.x, c0v.y, c0v.z, c0v.w,
                                     c1v.x, c1v.y, c1v.z, c1v.w};
#pragma unroll
                for (int a = 0; a < 4; ++a) {
#pragma unroll
                    for (int c = 0; c < 8; ++c) {
                        A[a][c] = __fmaf_rn(-cr[a], tc[c],
                                  __fmaf_rn(tr[a], cc[c], A[a][c]));
                    }
                }
            }
            if (P <= 13) stage(P + 2, P & 1);   // updated through P
        }
        if (wave == 0) crew(P + 1, true);       // panels 1..15
        __syncthreads();
    }

    if (t == 0) out[b] = pf;
}

extern "C" void kernel_launch(void* const* d_in, const int* in_sizes, int n_in,
                              void* d_out, int out_size, void* d_ws, size_t ws_size,
                              hipStream_t stream) {
    const float* x = (const float*)d_in[0];   // [128*128]
    const float* F = (const float*)d_in[1];   // [32640]
    float* out     = (float*)d_out;           // [128]
    (void)in_sizes; (void)n_in; (void)out_size; (void)d_ws; (void)ws_size;

    pfaffian_kernel<<<128, 512, 0, stream>>>(x, F, out);
}